// Round 6
// baseline (2258.228 us; speedup 1.0000x reference)
//
#include <hip/hip_runtime.h>
#include <math.h>

// Problem constants
#define B_ 8
#define S_ 2048
#define E_ 1024
#define H_ 8
#define D_ 128
#define LN_EPS 1e-5f
#define SCALE 0.08838834764831845f  // 1/sqrt(128)

typedef __attribute__((ext_vector_type(8))) short bf16x8;
typedef __attribute__((ext_vector_type(4))) float f32x4;
typedef unsigned short ushort_t;

__device__ __forceinline__ unsigned short f2bf(float f) {
  unsigned int u = __float_as_uint(f);
  unsigned int r = (u + 0x7fffu + ((u >> 16) & 1u)) >> 16;
  return (unsigned short)r;
}
__device__ __forceinline__ float bf2f(short v) {
  return __uint_as_float(((unsigned int)(unsigned short)v) << 16);
}

// async global->LDS, 16B per lane. LDS dest = wave-uniform base + lane*16.
typedef __attribute__((address_space(3))) unsigned int lds_u32;
typedef const __attribute__((address_space(1))) unsigned int glob_u32;
__device__ __forceinline__ void load_lds16(const void* g, void* l) {
  __builtin_amdgcn_global_load_lds((glob_u32*)g, (lds_u32*)l, 16, 0, 0);
}

// ---------------- cast fp32 -> bf16 (three segments, 8 elems/thread) -------

__global__ __launch_bounds__(256) void cast_bf16_kernel(
    const float* __restrict__ s0, ushort_t* __restrict__ d0, int n0,
    const float* __restrict__ s1, ushort_t* __restrict__ d1, int n1,
    const float* __restrict__ s2, ushort_t* __restrict__ d2, int n2) {
  int i = blockIdx.x * 256 + threadIdx.x;
  const float* s;
  ushort_t* d;
  int off;
  if (i < n0) { s = s0; d = d0; off = i; }
  else if (i < n0 + n1) { s = s1; d = d1; off = i - n0; }
  else if (i < n0 + n1 + n2) { s = s2; d = d2; off = i - n0 - n1; }
  else return;
  const float4 a = *(const float4*)(s + (size_t)off * 8);
  const float4 b = *(const float4*)(s + (size_t)off * 8 + 4);
  bf16x8 v;
  v[0] = (short)f2bf(a.x); v[1] = (short)f2bf(a.y);
  v[2] = (short)f2bf(a.z); v[3] = (short)f2bf(a.w);
  v[4] = (short)f2bf(b.x); v[5] = (short)f2bf(b.y);
  v[6] = (short)f2bf(b.z); v[7] = (short)f2bf(b.w);
  *(bf16x8*)(d + (size_t)off * 8) = v;
}

// ---------------- MFMA NT GEMM core (128x128 tile, BK=32) -------------------
// A [M,K] bf16, B [N,K] bf16, both K-contiguous. 256 thr = 4 waves (2x2 of 64x64).
// LDS staging via global_load_lds w/ XOR swizzle folded into the global address.

#define GEMM_BODY(A_, B_ptr, K_)                                               \
  const int tid = threadIdx.x;                                                 \
  const int wave = tid >> 6, lane = tid & 63;                                  \
  const int lrow = lane & 15, quad = lane >> 4;                                \
  const int wm = (wave >> 1) * 64, wn = (wave & 1) * 64;                       \
  const int row0 = blockIdx.y * 128, col0 = blockIdx.x * 128;                  \
  f32x4 acc[4][4] = {};                                                        \
  for (int k0 = 0; k0 < (K_); k0 += 32) {                                      \
    __syncthreads();                                                           \
    _Pragma("unroll")                                                          \
    for (int j = 0; j < 2; ++j) {                                              \
      const int cid = j * 256 + tid;                                           \
      const int r = cid >> 2, c = cid & 3;                                     \
      load_lds16((A_) + (size_t)(row0 + r) * (K_) + k0 + ((c ^ (r & 3)) * 8),  \
                 &sA[cid * 8]);                                                \
    }                                                                          \
    _Pragma("unroll")                                                          \
    for (int j = 0; j < 2; ++j) {                                              \
      const int cid = j * 256 + tid;                                           \
      const int r = cid >> 2, c = cid & 3;                                     \
      load_lds16((B_ptr) + (size_t)(col0 + r) * (K_) + k0 + ((c ^ (r & 3)) * 8),\
                 &sB[cid * 8]);                                                \
    }                                                                          \
    __syncthreads();                                                           \
    bf16x8 af[4], bf[4];                                                       \
    _Pragma("unroll")                                                          \
    for (int t = 0; t < 4; ++t) {                                              \
      const int ra = wm + t * 16 + lrow;                                       \
      af[t] = *(const bf16x8*)&sA[ra * 32 + (quad ^ (ra & 3)) * 8];            \
      const int rb = wn + t * 16 + lrow;                                       \
      bf[t] = *(const bf16x8*)&sB[rb * 32 + (quad ^ (rb & 3)) * 8];            \
    }                                                                          \
    _Pragma("unroll")                                                          \
    for (int ti = 0; ti < 4; ++ti)                                             \
      _Pragma("unroll")                                                        \
      for (int tj = 0; tj < 4; ++tj)                                           \
        acc[ti][tj] = __builtin_amdgcn_mfma_f32_16x16x32_bf16(                 \
            af[ti], bf[tj], acc[ti][tj], 0, 0, 0);                             \
  }

// ---- QKV GEMM: M=16384, N=3072, K=1024; epilogue -> Qs/Kb/Vt bf16 ----------

__global__ __launch_bounds__(256, 3) void gemm_mfma_qkv(
    const ushort_t* __restrict__ A, const ushort_t* __restrict__ Bw,
    const float* __restrict__ bias, ushort_t* __restrict__ Qs,
    ushort_t* __restrict__ Kb, ushort_t* __restrict__ Vt) {
  __shared__ ushort_t smem[16640];  // 33.3 KB: staging (16 KB) U transpose tile
  ushort_t* sA = smem;
  ushort_t* sB = smem + 4096;
  GEMM_BODY(A, Bw, E_)

  // epilogue: this block is entirely one of Q/K/V, one head, d-range 0..127
  const int ctile = blockIdx.x;          // 0..23
  const int kind = ctile >> 3;           // 0=Q 1=K 2=V
  const int h = ctile & 7;
  const int b = row0 >> 11, s0 = row0 & 2047;
  const float cs = (kind == 0) ? SCALE : 1.f;
  ushort_t* T = smem;                    // 128 x 130 (pad 2)

  __syncthreads();  // staging reads done before overwrite
  #pragma unroll
  for (int ti = 0; ti < 4; ++ti)
    #pragma unroll
    for (int tj = 0; tj < 4; ++tj) {
      const int col = wn + tj * 16 + lrow;
      const float bv = bias[ctile * 128 + col];
      #pragma unroll
      for (int r = 0; r < 4; ++r) {
        const int row = wm + ti * 16 + quad * 4 + r;
        T[row * 130 + col] = f2bf((acc[ti][tj][r] + bv) * cs);
      }
    }
  __syncthreads();

  if (kind <= 1) {  // row-major copy-out [b,h,s,d]
    ushort_t* dst = (kind == 0 ? Qs : Kb) + ((size_t)(b * H_ + h) * S_ + s0) * D_;
    const int s = tid >> 1, half = tid & 1;
    #pragma unroll
    for (int j = 0; j < 8; ++j) {
      bf16x8 v = *(const bf16x8*)&T[s * 130 + half * 64 + j * 8];
      *(bf16x8*)&dst[(size_t)s * D_ + half * 64 + j * 8] = v;
    }
  } else {  // transposed copy-out Vt[b,h,d,s]
    ushort_t* dst = Vt + (size_t)(b * H_ + h) * D_ * S_ + s0;
    const int d = tid >> 1, half = tid & 1;
    #pragma unroll
    for (int j = 0; j < 8; ++j) {
      bf16x8 v;
      #pragma unroll
      for (int jj = 0; jj < 8; ++jj)
        v[jj] = (short)T[(half * 64 + j * 8 + jj) * 130 + d];
      *(bf16x8*)&dst[(size_t)d * S_ + half * 64 + j * 8] = v;
    }
  }
}

// ---- out-proj GEMM: M=16384, N=1024, K=1024; fp32 epilogue + bias + res ----

__global__ __launch_bounds__(256, 3) void gemm_mfma_out(
    const ushort_t* __restrict__ A, const ushort_t* __restrict__ Bw,
    const float* __restrict__ bias, const float* __restrict__ res,
    float* __restrict__ C) {
  __shared__ ushort_t smem[16640];
  ushort_t* sA = smem;
  ushort_t* sB = smem + 4096;
  GEMM_BODY(A, Bw, E_)

  #pragma unroll
  for (int ti = 0; ti < 4; ++ti)
    #pragma unroll
    for (int tj = 0; tj < 4; ++tj) {
      const int col = col0 + wn + tj * 16 + lrow;
      const float bv = bias[col];
      #pragma unroll
      for (int r = 0; r < 4; ++r) {
        const int row = row0 + wm + ti * 16 + quad * 4 + r;
        const size_t idx = (size_t)row * E_ + col;
        C[idx] = acc[ti][tj][r] + bv + res[idx];
      }
    }
}

// ---------------- MFMA attention, split + key-halved (R6) -------------------
// R5 post-mortem: attention stuck at ~135us/dispatch with 46% occupancy in
// EVERY round -> the 64KB Plds (2 blocks/CU, 16 waves/CU) is the invariant
// cap on latency hiding. R6: process keys in 2 halves of 1024 so Plds is
// 16x1032 bf16 = 33KB -> 4 blocks/CU -> 32 waves/CU. launch_bounds(512,8)
// pins the 64-VGPR budget this occupancy needs (QK depth-1: live set ~55).
// Row stride 1032 (pad 8) spreads Plds row bases across banks (R5: every
// row base hit bank 0 -> ~8-way conflict on every PV ds_read_b128).
// PV accumulates unnormalized over halves; rowsums accumulate in registers;
// one normalize at the end. P dumped per half (same bytes as R5).

#define ROWSTR 1032

__device__ __forceinline__ void loadk4(bf16x8 k[4], const ushort_t* kp) {
  k[0] = *(const bf16x8*)(kp);
  k[1] = *(const bf16x8*)(kp + 32);
  k[2] = *(const bf16x8*)(kp + 64);
  k[3] = *(const bf16x8*)(kp + 96);
}

__global__ __launch_bounds__(512, 8) void attn_qk_pv(
    const ushort_t* __restrict__ Qs, const ushort_t* __restrict__ Kb,
    const ushort_t* __restrict__ Vt, ushort_t* __restrict__ ctx,
    ushort_t* __restrict__ Pd, float* __restrict__ Pinv, int b) {
  __shared__ ushort_t Plds[16 * ROWSTR];  // 33 KB swizzled probs (one half)
  __shared__ float swred[8][16];          // [wave][row] rowsum partials
  const int tid = threadIdx.x;
  const int wave = tid >> 6;   // 0..7
  const int lane = tid & 63;
  const int lrow = lane & 15;
  const int quad = lane >> 4;
  const int x7 = lrow & 7;
  const int h = blockIdx.x & 7;         // head h -> XCD h
  const int q0 = (blockIdx.x >> 3) * 16;

  const ushort_t* Qh = Qs + ((size_t)(b * H_ + h)) * S_ * D_;
  const ushort_t* Kh = Kb + ((size_t)(b * H_ + h)) * S_ * D_;
  const ushort_t* Vh = Vt + ((size_t)(b * H_ + h)) * D_ * S_;

  bf16x8 qf[4];
  #pragma unroll
  for (int t = 0; t < 4; ++t)
    qf[t] = *(const bf16x8*)(Qh + (size_t)(q0 + lrow) * D_ + t * 32 + quad * 8);

  float rs4[4] = {0.f, 0.f, 0.f, 0.f};
  f32x4 c0 = {0.f, 0.f, 0.f, 0.f}, c1 = {0.f, 0.f, 0.f, 0.f};

  for (int kh = 0; kh < 2; ++kh) {
    const int kbase = kh << 10;  // global key offset of this half

    // ---- QK^T + exp -> swizzled Plds; rowsums accumulate in registers ----
    // wave owns 8 key-tiles (128 keys) of this half
    const int ct0 = wave * 8;
    const ushort_t* Kp =
        Kh + (size_t)(kbase + ct0 * 16 + lrow) * D_ + (quad << 3);
    #pragma unroll
    for (int ip = 0; ip < 8; ++ip) {
      bf16x8 k0[4];
      loadk4(k0, Kp + (size_t)ip * 16 * D_);
      f32x4 a0 = {0.f, 0.f, 0.f, 0.f};
      #pragma unroll
      for (int t = 0; t < 4; ++t)
        a0 = __builtin_amdgcn_mfma_f32_16x16x32_bf16(qf[t], k0[t], a0, 0, 0, 0);
      #pragma unroll
      for (int r = 0; r < 4; ++r) {
        const int row = (quad << 2) + r;
        const int key = ((ct0 + ip) << 4) | lrow;  // 0..1023 within half
        const unsigned short us = f2bf(__expf(a0[r]));
        Plds[row * ROWSTR + ((((key >> 3) ^ (row & 7)) << 3) | (key & 7))] = us;
        rs4[r] += bf2f((short)us);
      }
    }
    __syncthreads();  // Plds half ready for dump + PV

    // ---- dump half (deswizzled): thread = (row, seg); seg-major for banks --
    {
      const int row = tid >> 5;
      const int seg = tid & 31;
      const ushort_t* src = &Plds[row * ROWSTR];
      ushort_t* dst = Pd + ((size_t)h * S_ + q0 + row) * S_ + kbase;
      #pragma unroll
      for (int j = 0; j < 4; ++j) {
        const int blk8 = seg + 32 * j;  // 0..127
        *(bf16x8*)(dst + blk8 * 8) =
            *(const bf16x8*)&src[(blk8 ^ (row & 7)) << 3];
      }
    }

    // ---- PV half: wave owns d-slice [wave*16,+16), 32 steps, depth-2 ------
    {
      const ushort_t* Vd =
          Vh + (size_t)(wave * 16 + lrow) * S_ + kbase + (quad << 3);
      const ushort_t* Prow = Plds + lrow * ROWSTR;
      bf16x8 pa0, pv0, pa1, pv1;
#define PVLD(A_, V_, KT_)                                                      \
  {                                                                            \
    A_ = *(const bf16x8*)&Prow[(((((KT_) << 2) + quad) ^ x7) << 3)];           \
    V_ = *(const bf16x8*)(Vd + ((KT_) << 5));                                  \
  }
      PVLD(pa0, pv0, 0); PVLD(pa1, pv1, 1);
      #pragma unroll
      for (int t = 0; t < 15; ++t) {
        c0 = __builtin_amdgcn_mfma_f32_16x16x32_bf16(pa0, pv0, c0, 0, 0, 0);
        PVLD(pa0, pv0, 2 * t + 2);
        c1 = __builtin_amdgcn_mfma_f32_16x16x32_bf16(pa1, pv1, c1, 0, 0, 0);
        PVLD(pa1, pv1, 2 * t + 3);
      }
      c0 = __builtin_amdgcn_mfma_f32_16x16x32_bf16(pa0, pv0, c0, 0, 0, 0);
      c1 = __builtin_amdgcn_mfma_f32_16x16x32_bf16(pa1, pv1, c1, 0, 0, 0);
#undef PVLD
    }
    __syncthreads();  // Plds reads done before next half overwrites
  }

  // ---- rowsums: butterfly over the 16 lanes (lrow) -> per-wave partials ---
  #pragma unroll
  for (int r = 0; r < 4; ++r) {
    #pragma unroll
    for (int off = 1; off < 16; off <<= 1) rs4[r] += __shfl_xor(rs4[r], off);
  }
  if (lrow == 0) {
    #pragma unroll
    for (int r = 0; r < 4; ++r) swred[wave][(quad << 2) + r] = rs4[r];
  }
  __syncthreads();

  // ---- per-lane inverse for row lrow; distribute via shfl -----------------
  float invr;
  {
    float s = 0.f;
    #pragma unroll
    for (int w = 0; w < 8; ++w) s += swred[w][lrow];
    invr = 1.f / s;
  }
  if (tid < 16) Pinv[h * S_ + q0 + tid] = invr;
  float inv4[4];
  #pragma unroll
  for (int r = 0; r < 4; ++r) inv4[r] = __shfl(invr, (quad << 2) + r);

  // ---- scale + write ctx ---------------------------------------------------
  #pragma unroll
  for (int r = 0; r < 4; ++r) {
    const int row = (quad << 2) + r;
    ctx[((size_t)(b * S_ + q0 + row)) * E_ + h * D_ + wave * 16 + lrow] =
        f2bf((c0[r] + c1[r]) * inv4[r]);
  }
}

// ---- kernel B: attn_out[b] = mean over heads of P * inv --------------------

__global__ __launch_bounds__(256) void attn_avg(
    const ushort_t* __restrict__ Pd, const float* __restrict__ Pinv,
    float* __restrict__ attn_out_b) {
  const int q = blockIdx.x;            // 0..2047
  const int k0 = threadIdx.x * 8;
  float acc[8] = {};
  #pragma unroll
  for (int h = 0; h < H_; ++h) {
    const float w = Pinv[h * S_ + q] * 0.125f;
    const bf16x8 v = *(const bf16x8*)(Pd + ((size_t)h * S_ + q) * S_ + k0);
    #pragma unroll
    for (int j = 0; j < 8; ++j) acc[j] += bf2f(v[j]) * w;
  }
  float4 v0 = {acc[0], acc[1], acc[2], acc[3]};
  float4 v1 = {acc[4], acc[5], acc[6], acc[7]};
  *(float4*)(attn_out_b + (size_t)q * S_ + k0) = v0;
  *(float4*)(attn_out_b + (size_t)q * S_ + k0 + 4) = v1;
}

// ---------------- LayerNorm stats: one block per row -----------------------

__device__ __forceinline__ float block_reduce_sum1(float v, float* red) {
  #pragma unroll
  for (int off = 32; off > 0; off >>= 1) v += __shfl_down(v, off);
  const int tid = threadIdx.x;
  __syncthreads();
  if ((tid & 63) == 0) red[tid >> 6] = v;
  __syncthreads();
  return (red[0] + red[1]) + (red[2] + red[3]);
}

__global__ __launch_bounds__(256) void ln_stats_kernel(
    const float* __restrict__ ypre, float* __restrict__ stats) {
  __shared__ float red[4];
  const int row = blockIdx.x;
  const int tid = threadIdx.x;
  const float* p = ypre + (size_t)row * E_;
  float4 v = *(const float4*)(p + tid * 4);
  float s = (v.x + v.y) + (v.z + v.w);
  s = block_reduce_sum1(s, red);
  const float mu = s * (1.f / E_);
  float e0 = v.x - mu, e1 = v.y - mu, e2 = v.z - mu, e3 = v.w - mu;
  float ss = (e0 * e0 + e1 * e1) + (e2 * e2 + e3 * e3);
  ss = block_reduce_sum1(ss, red);
  if (tid == 0) {
    stats[(size_t)row * 2 + 0] = mu;
    stats[(size_t)row * 2 + 1] = rsqrtf(ss * (1.f / E_) + LN_EPS);
  }
}

// ---------------- context: two-stage mean over s ---------------------------

__global__ __launch_bounds__(256) void context_partial(
    const float* __restrict__ ypre, const float* __restrict__ stats,
    float* __restrict__ part) {
  const int e = blockIdx.x * 256 + threadIdx.x;
  const int b = blockIdx.y;
  const int c = blockIdx.z;
  float acc = 0.f;
  for (int s = c * 128; s < c * 128 + 128; ++s) {
    const size_t row = (size_t)b * S_ + s;
    acc += (ypre[row * E_ + e] - stats[row * 2]) * stats[row * 2 + 1];
  }
  part[((size_t)(b * 16 + c)) * E_ + e] = acc;
}

__global__ __launch_bounds__(256) void context_final(
    const float* __restrict__ part, const float* __restrict__ g,
    const float* __restrict__ bb, float* __restrict__ outctx) {
  const int idx = blockIdx.x * 256 + threadIdx.x;  // b*E + e
  const int b = idx >> 10, e = idx & 1023;
  float acc = 0.f;
  #pragma unroll
  for (int c = 0; c < 16; ++c) acc += part[((size_t)(b * 16 + c)) * E_ + e];
  outctx[idx] = acc * (1.f / S_) * g[e] + bb[e];
}

// ---------------- launcher --------------------------------------------------

extern "C" void kernel_launch(void* const* d_in, const int* in_sizes, int n_in,
                              void* d_out, int out_size, void* d_ws, size_t ws_size,
                              hipStream_t stream) {
  const float* x     = (const float*)d_in[0];
  const float* in_w  = (const float*)d_in[1];
  const float* in_b  = (const float*)d_in[2];
  const float* out_w = (const float*)d_in[3];
  const float* out_b = (const float*)d_in[4];
  const float* ln_g  = (const float*)d_in[5];
  const float* ln_b  = (const float*)d_in[6];

  float* out_ctx  = (float*)d_out;              // [B, E]
  float* out_attn = out_ctx + (size_t)B_ * E_;  // [B, S, S]

  // ws layout (<= 234 MB proven available):
  char* ws = (char*)d_ws;
  const size_t MB = 1024 * 1024;
  ushort_t* xb     = (ushort_t*)(ws);            // x bf16        32 MB
  ushort_t* Qs     = (ushort_t*)(ws + 32 * MB);  // [B,H,S,D]     32 MB
  ushort_t* Kb     = (ushort_t*)(ws + 64 * MB);  // [B,H,S,D]     32 MB
  ushort_t* Vt     = (ushort_t*)(ws + 96 * MB);  // [B,H,D,S]     32 MB
  ushort_t* ctxb16 = (ushort_t*)(ws + 128 * MB); // [B,S,E] bf16  32 MB
  float*    ypre   = (float*)(ws + 160 * MB);    // fp32          64 MB
  ushort_t* wb     = (ushort_t*)(ws + 224 * MB); // in_w bf16      6 MB
  ushort_t* owb    = (ushort_t*)(ws + 230 * MB); // out_w bf16     2 MB
  float*    stats  = (float*)(ws + 232 * MB);    // (mu,rs)      128 KB
  float*    part   = (float*)(ws + 233 * MB);    // ctx partials 512 KB
  // P chunk [H,S,S] bf16 = 67.1 MB, lives in ypre+wb region (both dead
  // during the attention phase: wb consumed by QKV gemm; ypre written after).
  ushort_t* Pchunk = (ushort_t*)(ws + 160 * MB);
  float*    Pinv   = (float*)(ws + 233 * MB + 512 * 1024);  // [H,S] 64 KB

  // 0) cast x / in_w / out_w to bf16
  const int n0 = B_ * S_ * E_ / 8, n1 = 3 * E_ * E_ / 8, n2 = E_ * E_ / 8;
  cast_bf16_kernel<<<(n0 + n1 + n2) / 256, 256, 0, stream>>>(
      x, xb, n0, in_w, wb, n1, out_w, owb, n2);

  // 1) QKV projection (MFMA), epilogue -> Qs(scaled)/Kb/Vt bf16
  gemm_mfma_qkv<<<dim3(3 * E_ / 128, B_ * S_ / 128), 256, 0, stream>>>(
      xb, wb, in_b, Qs, Kb, Vt);

  // 2) attention per batch: A (QK+PV+ctx+P dump) then B (head-average)
  for (int b = 0; b < B_; ++b) {
    attn_qk_pv<<<(S_ / 16) * H_, 512, 0, stream>>>(
        Qs, Kb, Vt, ctxb16, Pchunk, Pinv, b);
    attn_avg<<<S_, 256, 0, stream>>>(
        Pchunk, Pinv, out_attn + (size_t)b * S_ * S_);
  }

  // 3) ypre = ctx @ out_w^T + out_b + x (MFMA, fp32 epilogue)
  gemm_mfma_out<<<dim3(E_ / 128, B_ * S_ / 128), 256, 0, stream>>>(
      ctxb16, owb, out_b, x, ypre);

  // 4) LN row stats
  ln_stats_kernel<<<B_ * S_, 256, 0, stream>>>(ypre, stats);

  // 5) context = mean over s of LN(ypre)*g + b (two-stage)
  context_partial<<<dim3(E_ / 256, B_, 16), 256, 0, stream>>>(ypre, stats, part);
  context_final<<<B_ * E_ / 256, 256, 0, stream>>>(part, ln_g, ln_b, out_ctx);
}

// Round 7
// 1204.050 us; speedup vs baseline: 1.8755x; 1.8755x over previous
//
#include <hip/hip_runtime.h>
#include <math.h>

// Problem constants
#define B_ 8
#define S_ 2048
#define E_ 1024
#define H_ 8
#define D_ 128
#define LN_EPS 1e-5f
#define SCALE 0.08838834764831845f  // 1/sqrt(128)

typedef __attribute__((ext_vector_type(8))) short bf16x8;
typedef __attribute__((ext_vector_type(4))) float f32x4;
typedef unsigned short ushort_t;

__device__ __forceinline__ unsigned short f2bf(float f) {
  unsigned int u = __float_as_uint(f);
  unsigned int r = (u + 0x7fffu + ((u >> 16) & 1u)) >> 16;
  return (unsigned short)r;
}
__device__ __forceinline__ float bf2f(short v) {
  return __uint_as_float(((unsigned int)(unsigned short)v) << 16);
}

// async global->LDS, 16B per lane. LDS dest = wave-uniform base + lane*16.
typedef __attribute__((address_space(3))) unsigned int lds_u32;
typedef const __attribute__((address_space(1))) unsigned int glob_u32;
__device__ __forceinline__ void load_lds16(const void* g, void* l) {
  __builtin_amdgcn_global_load_lds((glob_u32*)g, (lds_u32*)l, 16, 0, 0);
}

// ---------------- cast fp32 -> bf16 (three segments, 8 elems/thread) -------

__global__ __launch_bounds__(256) void cast_bf16_kernel(
    const float* __restrict__ s0, ushort_t* __restrict__ d0, int n0,
    const float* __restrict__ s1, ushort_t* __restrict__ d1, int n1,
    const float* __restrict__ s2, ushort_t* __restrict__ d2, int n2) {
  int i = blockIdx.x * 256 + threadIdx.x;
  const float* s;
  ushort_t* d;
  int off;
  if (i < n0) { s = s0; d = d0; off = i; }
  else if (i < n0 + n1) { s = s1; d = d1; off = i - n0; }
  else if (i < n0 + n1 + n2) { s = s2; d = d2; off = i - n0 - n1; }
  else return;
  const float4 a = *(const float4*)(s + (size_t)off * 8);
  const float4 b = *(const float4*)(s + (size_t)off * 8 + 4);
  bf16x8 v;
  v[0] = (short)f2bf(a.x); v[1] = (short)f2bf(a.y);
  v[2] = (short)f2bf(a.z); v[3] = (short)f2bf(a.w);
  v[4] = (short)f2bf(b.x); v[5] = (short)f2bf(b.y);
  v[6] = (short)f2bf(b.z); v[7] = (short)f2bf(b.w);
  *(bf16x8*)(d + (size_t)off * 8) = v;
}

// ---------------- MFMA NT GEMM core (128x128 tile, BK=32) -------------------
// A [M,K] bf16, B [N,K] bf16, both K-contiguous. 256 thr = 4 waves (2x2 of 64x64).
// LDS staging via global_load_lds w/ XOR swizzle folded into the global address.

#define GEMM_BODY(A_, B_ptr, K_)                                               \
  const int tid = threadIdx.x;                                                 \
  const int wave = tid >> 6, lane = tid & 63;                                  \
  const int lrow = lane & 15, quad = lane >> 4;                                \
  const int wm = (wave >> 1) * 64, wn = (wave & 1) * 64;                       \
  const int row0 = blockIdx.y * 128, col0 = blockIdx.x * 128;                  \
  f32x4 acc[4][4] = {};                                                        \
  for (int k0 = 0; k0 < (K_); k0 += 32) {                                      \
    __syncthreads();                                                           \
    _Pragma("unroll")                                                          \
    for (int j = 0; j < 2; ++j) {                                              \
      const int cid = j * 256 + tid;                                           \
      const int r = cid >> 2, c = cid & 3;                                     \
      load_lds16((A_) + (size_t)(row0 + r) * (K_) + k0 + ((c ^ (r & 3)) * 8),  \
                 &sA[cid * 8]);                                                \
    }                                                                          \
    _Pragma("unroll")                                                          \
    for (int j = 0; j < 2; ++j) {                                              \
      const int cid = j * 256 + tid;                                           \
      const int r = cid >> 2, c = cid & 3;                                     \
      load_lds16((B_ptr) + (size_t)(col0 + r) * (K_) + k0 + ((c ^ (r & 3)) * 8),\
                 &sB[cid * 8]);                                                \
    }                                                                          \
    __syncthreads();                                                           \
    bf16x8 af[4], bf[4];                                                       \
    _Pragma("unroll")                                                          \
    for (int t = 0; t < 4; ++t) {                                              \
      const int ra = wm + t * 16 + lrow;                                       \
      af[t] = *(const bf16x8*)&sA[ra * 32 + (quad ^ (ra & 3)) * 8];            \
      const int rb = wn + t * 16 + lrow;                                       \
      bf[t] = *(const bf16x8*)&sB[rb * 32 + (quad ^ (rb & 3)) * 8];            \
    }                                                                          \
    _Pragma("unroll")                                                          \
    for (int ti = 0; ti < 4; ++ti)                                             \
      _Pragma("unroll")                                                        \
      for (int tj = 0; tj < 4; ++tj)                                           \
        acc[ti][tj] = __builtin_amdgcn_mfma_f32_16x16x32_bf16(                 \
            af[ti], bf[tj], acc[ti][tj], 0, 0, 0);                             \
  }

// ---- QKV GEMM: M=16384, N=3072, K=1024; epilogue -> Qs/Kb/Vt bf16 ----------

__global__ __launch_bounds__(256, 3) void gemm_mfma_qkv(
    const ushort_t* __restrict__ A, const ushort_t* __restrict__ Bw,
    const float* __restrict__ bias, ushort_t* __restrict__ Qs,
    ushort_t* __restrict__ Kb, ushort_t* __restrict__ Vt) {
  __shared__ ushort_t smem[16640];  // 33.3 KB: staging (16 KB) U transpose tile
  ushort_t* sA = smem;
  ushort_t* sB = smem + 4096;
  GEMM_BODY(A, Bw, E_)

  // epilogue: this block is entirely one of Q/K/V, one head, d-range 0..127
  const int ctile = blockIdx.x;          // 0..23
  const int kind = ctile >> 3;           // 0=Q 1=K 2=V
  const int h = ctile & 7;
  const int b = row0 >> 11, s0 = row0 & 2047;
  const float cs = (kind == 0) ? SCALE : 1.f;
  ushort_t* T = smem;                    // 128 x 130 (pad 2)

  __syncthreads();  // staging reads done before overwrite
  #pragma unroll
  for (int ti = 0; ti < 4; ++ti)
    #pragma unroll
    for (int tj = 0; tj < 4; ++tj) {
      const int col = wn + tj * 16 + lrow;
      const float bv = bias[ctile * 128 + col];
      #pragma unroll
      for (int r = 0; r < 4; ++r) {
        const int row = wm + ti * 16 + quad * 4 + r;
        T[row * 130 + col] = f2bf((acc[ti][tj][r] + bv) * cs);
      }
    }
  __syncthreads();

  if (kind <= 1) {  // row-major copy-out [b,h,s,d]
    ushort_t* dst = (kind == 0 ? Qs : Kb) + ((size_t)(b * H_ + h) * S_ + s0) * D_;
    const int s = tid >> 1, half = tid & 1;
    #pragma unroll
    for (int j = 0; j < 8; ++j) {
      bf16x8 v = *(const bf16x8*)&T[s * 130 + half * 64 + j * 8];
      *(bf16x8*)&dst[(size_t)s * D_ + half * 64 + j * 8] = v;
    }
  } else {  // transposed copy-out Vt[b,h,d,s]
    ushort_t* dst = Vt + (size_t)(b * H_ + h) * D_ * S_ + s0;
    const int d = tid >> 1, half = tid & 1;
    #pragma unroll
    for (int j = 0; j < 8; ++j) {
      bf16x8 v;
      #pragma unroll
      for (int jj = 0; jj < 8; ++jj)
        v[jj] = (short)T[(half * 64 + j * 8 + jj) * 130 + d];
      *(bf16x8*)&dst[(size_t)d * S_ + half * 64 + j * 8] = v;
    }
  }
}

// ---- out-proj GEMM: M=16384, N=1024, K=1024; fp32 epilogue + bias + res ----

__global__ __launch_bounds__(256, 3) void gemm_mfma_out(
    const ushort_t* __restrict__ A, const ushort_t* __restrict__ Bw,
    const float* __restrict__ bias, const float* __restrict__ res,
    float* __restrict__ C) {
  __shared__ ushort_t smem[16640];
  ushort_t* sA = smem;
  ushort_t* sB = smem + 4096;
  GEMM_BODY(A, Bw, E_)

  #pragma unroll
  for (int ti = 0; ti < 4; ++ti)
    #pragma unroll
    for (int tj = 0; tj < 4; ++tj) {
      const int col = col0 + wn + tj * 16 + lrow;
      const float bv = bias[col];
      #pragma unroll
      for (int r = 0; r < 4; ++r) {
        const int row = row0 + wm + ti * 16 + quad * 4 + r;
        const size_t idx = (size_t)row * E_ + col;
        C[idx] = acc[ti][tj][r] + bv + res[idx];
      }
    }
}

// ---------------- attention as three GEMM-shaped passes (R7) ----------------
// R6 post-mortem: attention was MLP-starved (depth-4 register pipeline = ~4
// outstanding loads/wave; Little's law caps chip BW at ~700 GB/s — matches
// every measured attn round). Fix: reuse GEMM_BODY's global_load_lds bulk
// staging (deep async queue, no VGPR cost) for attention itself:
//   1) qk_gemm_exp: P[q,k] = exp(Q.K^T) (K=128), epilogue stages exp via LDS,
//      coalesced bf16 P write + per-row partial rowsums via atomicAdd.
//   2) pv_gemm: ctx = (P.V)/rowsum (K=2048, B = Vt already [d,s] NT layout).
//   3) attn_avg: head-average of P with w = 1/(8*rowsum).
// Numerics chain identical to R5: bf16-rounded exp, fp32 sums, bf16 MFMA PV.

__global__ __launch_bounds__(256) void zero_rsum_kernel(float* __restrict__ p) {
  p[blockIdx.x * 256 + threadIdx.x] = 0.f;
}

__global__ __launch_bounds__(256, 3) void qk_gemm_exp(
    const ushort_t* __restrict__ Qs, const ushort_t* __restrict__ Kb,
    ushort_t* __restrict__ P, float* __restrict__ rsum, int b) {
  __shared__ ushort_t smem[16640];
  ushort_t* sA = smem;
  ushort_t* sB = smem + 4096;
  const int h = blockIdx.z;
  const ushort_t* A = Qs + (size_t)(b * H_ + h) * S_ * D_;
  const ushort_t* Bp = Kb + (size_t)(b * H_ + h) * S_ * D_;
  GEMM_BODY(A, Bp, D_)

  // ---- epilogue: exp -> LDS tile, then coalesced P write + rowsums --------
  ushort_t* T = smem;  // 128 x 130
  __syncthreads();
  #pragma unroll
  for (int ti = 0; ti < 4; ++ti)
    #pragma unroll
    for (int tj = 0; tj < 4; ++tj) {
      const int col = wn + tj * 16 + lrow;
      #pragma unroll
      for (int r = 0; r < 4; ++r) {
        const int row = wm + ti * 16 + quad * 4 + r;
        T[row * 130 + col] = f2bf(__expf(acc[ti][tj][r]));
      }
    }
  __syncthreads();

  {
    const int rr = tid >> 1, half = tid & 1;  // row 0..127, col-half
    ushort_t* dst = P + ((size_t)h * S_ + row0 + rr) * S_ + col0 + half * 64;
    const ushort_t* src = &T[rr * 130 + half * 64];
    float s = 0.f;
    #pragma unroll
    for (int j = 0; j < 8; ++j) {
      const bf16x8 v = *(const bf16x8*)(src + j * 8);
      *(bf16x8*)(dst + j * 8) = v;
      #pragma unroll
      for (int jj = 0; jj < 8; ++jj) s += bf2f(v[jj]);
    }
    s += __shfl_xor(s, 1);  // combine the two col-halves (adjacent lanes)
    if (half == 0)
      atomicAdd(&rsum[(size_t)(b * H_ + h) * S_ + row0 + rr], s);
  }
}

__global__ __launch_bounds__(256, 3) void pv_gemm(
    const ushort_t* __restrict__ P, const ushort_t* __restrict__ Vt,
    const float* __restrict__ rsum, ushort_t* __restrict__ ctx, int b) {
  __shared__ ushort_t smem[16640];
  ushort_t* sA = smem;
  ushort_t* sB = smem + 4096;
  const int h = blockIdx.z;
  const ushort_t* A = P + (size_t)h * S_ * S_;
  const ushort_t* Bp = Vt + (size_t)(b * H_ + h) * D_ * S_;
  GEMM_BODY(A, Bp, S_)

  // ---- epilogue: normalize by rowsum -> LDS tile -> coalesced ctx write ---
  ushort_t* T = smem;  // 128 x 130
  __syncthreads();
  const float* rs = rsum + (size_t)(b * H_ + h) * S_ + row0;
  #pragma unroll
  for (int ti = 0; ti < 4; ++ti)
    #pragma unroll
    for (int r = 0; r < 4; ++r) {
      const int row = wm + ti * 16 + quad * 4 + r;
      const float inv = 1.f / rs[row];
      #pragma unroll
      for (int tj = 0; tj < 4; ++tj) {
        const int col = wn + tj * 16 + lrow;
        T[row * 130 + col] = f2bf(acc[ti][tj][r] * inv);
      }
    }
  __syncthreads();

  {
    const int rr = tid >> 1, half = tid & 1;
    ushort_t* dst =
        ctx + ((size_t)(b * S_ + row0 + rr)) * E_ + h * D_ + half * 64;
    const ushort_t* src = &T[rr * 130 + half * 64];
    #pragma unroll
    for (int j = 0; j < 8; ++j)
      *(bf16x8*)(dst + j * 8) = *(const bf16x8*)(src + j * 8);
  }
}

// ---- attn_out[b] = mean over heads of P * inv ------------------------------

__global__ __launch_bounds__(256) void attn_avg(
    const ushort_t* __restrict__ P, const float* __restrict__ rsum_b,
    float* __restrict__ attn_out_b) {
  const int q = blockIdx.x;            // 0..2047
  const int k0 = threadIdx.x * 8;
  float acc[8] = {};
  #pragma unroll
  for (int h = 0; h < H_; ++h) {
    const float w = 0.125f / rsum_b[h * S_ + q];
    const bf16x8 v = *(const bf16x8*)(P + ((size_t)h * S_ + q) * S_ + k0);
    #pragma unroll
    for (int j = 0; j < 8; ++j) acc[j] += bf2f(v[j]) * w;
  }
  float4 v0 = {acc[0], acc[1], acc[2], acc[3]};
  float4 v1 = {acc[4], acc[5], acc[6], acc[7]};
  *(float4*)(attn_out_b + (size_t)q * S_ + k0) = v0;
  *(float4*)(attn_out_b + (size_t)q * S_ + k0 + 4) = v1;
}

// ---------------- LayerNorm stats: one block per row -----------------------

__device__ __forceinline__ float block_reduce_sum1(float v, float* red) {
  #pragma unroll
  for (int off = 32; off > 0; off >>= 1) v += __shfl_down(v, off);
  const int tid = threadIdx.x;
  __syncthreads();
  if ((tid & 63) == 0) red[tid >> 6] = v;
  __syncthreads();
  return (red[0] + red[1]) + (red[2] + red[3]);
}

__global__ __launch_bounds__(256) void ln_stats_kernel(
    const float* __restrict__ ypre, float* __restrict__ stats) {
  __shared__ float red[4];
  const int row = blockIdx.x;
  const int tid = threadIdx.x;
  const float* p = ypre + (size_t)row * E_;
  float4 v = *(const float4*)(p + tid * 4);
  float s = (v.x + v.y) + (v.z + v.w);
  s = block_reduce_sum1(s, red);
  const float mu = s * (1.f / E_);
  float e0 = v.x - mu, e1 = v.y - mu, e2 = v.z - mu, e3 = v.w - mu;
  float ss = (e0 * e0 + e1 * e1) + (e2 * e2 + e3 * e3);
  ss = block_reduce_sum1(ss, red);
  if (tid == 0) {
    stats[(size_t)row * 2 + 0] = mu;
    stats[(size_t)row * 2 + 1] = rsqrtf(ss * (1.f / E_) + LN_EPS);
  }
}

// ---------------- context: two-stage mean over s ---------------------------

__global__ __launch_bounds__(256) void context_partial(
    const float* __restrict__ ypre, const float* __restrict__ stats,
    float* __restrict__ part) {
  const int e = blockIdx.x * 256 + threadIdx.x;
  const int b = blockIdx.y;
  const int c = blockIdx.z;
  float acc = 0.f;
  for (int s = c * 128; s < c * 128 + 128; ++s) {
    const size_t row = (size_t)b * S_ + s;
    acc += (ypre[row * E_ + e] - stats[row * 2]) * stats[row * 2 + 1];
  }
  part[((size_t)(b * 16 + c)) * E_ + e] = acc;
}

__global__ __launch_bounds__(256) void context_final(
    const float* __restrict__ part, const float* __restrict__ g,
    const float* __restrict__ bb, float* __restrict__ outctx) {
  const int idx = blockIdx.x * 256 + threadIdx.x;  // b*E + e
  const int b = idx >> 10, e = idx & 1023;
  float acc = 0.f;
  #pragma unroll
  for (int c = 0; c < 16; ++c) acc += part[((size_t)(b * 16 + c)) * E_ + e];
  outctx[idx] = acc * (1.f / S_) * g[e] + bb[e];
}

// ---------------- launcher --------------------------------------------------

extern "C" void kernel_launch(void* const* d_in, const int* in_sizes, int n_in,
                              void* d_out, int out_size, void* d_ws, size_t ws_size,
                              hipStream_t stream) {
  const float* x     = (const float*)d_in[0];
  const float* in_w  = (const float*)d_in[1];
  const float* in_b  = (const float*)d_in[2];
  const float* out_w = (const float*)d_in[3];
  const float* out_b = (const float*)d_in[4];
  const float* ln_g  = (const float*)d_in[5];
  const float* ln_b  = (const float*)d_in[6];

  float* out_ctx  = (float*)d_out;              // [B, E]
  float* out_attn = out_ctx + (size_t)B_ * E_;  // [B, S, S]

  // ws layout (<= 234 MB proven available):
  char* ws = (char*)d_ws;
  const size_t MB = 1024 * 1024;
  ushort_t* xb     = (ushort_t*)(ws);            // x bf16        32 MB
  ushort_t* Qs     = (ushort_t*)(ws + 32 * MB);  // [B,H,S,D]     32 MB
  ushort_t* Kb     = (ushort_t*)(ws + 64 * MB);  // [B,H,S,D]     32 MB
  ushort_t* Vt     = (ushort_t*)(ws + 96 * MB);  // [B,H,D,S]     32 MB
  ushort_t* ctxb16 = (ushort_t*)(ws + 128 * MB); // [B,S,E] bf16  32 MB
  float*    ypre   = (float*)(ws + 160 * MB);    // fp32          64 MB
  ushort_t* wb     = (ushort_t*)(ws + 224 * MB); // in_w bf16      6 MB
  ushort_t* owb    = (ushort_t*)(ws + 230 * MB); // out_w bf16     2 MB
  float*    stats  = (float*)(ws + 232 * MB);    // (mu,rs)      128 KB
  float*    part   = (float*)(ws + 233 * MB);    // ctx partials 512 KB
  // P chunk [H,S,S] bf16 = 67.1 MB lives in ypre+wb region (both dead during
  // the attention phase: wb consumed by QKV gemm; ypre written after; owb at
  // +230 MB is untouched since P ends at +227.1 MB).
  ushort_t* Pchunk = (ushort_t*)(ws + 160 * MB);
  float*    rsum   = (float*)(ws + 233 * MB + 512 * 1024);  // [B,H,S] 512 KB

  // 0) cast x / in_w / out_w to bf16
  const int n0 = B_ * S_ * E_ / 8, n1 = 3 * E_ * E_ / 8, n2 = E_ * E_ / 8;
  cast_bf16_kernel<<<(n0 + n1 + n2) / 256, 256, 0, stream>>>(
      x, xb, n0, in_w, wb, n1, out_w, owb, n2);

  // zero all rowsum accumulators (B*H*S floats = 128K)
  zero_rsum_kernel<<<B_ * H_ * S_ / 256, 256, 0, stream>>>(rsum);

  // 1) QKV projection (MFMA), epilogue -> Qs(scaled)/Kb/Vt bf16
  gemm_mfma_qkv<<<dim3(3 * E_ / 128, B_ * S_ / 128), 256, 0, stream>>>(
      xb, wb, in_b, Qs, Kb, Vt);

  // 2) attention per batch: QK^T+exp GEMM, PV GEMM, head-average
  for (int b = 0; b < B_; ++b) {
    qk_gemm_exp<<<dim3(S_ / 128, S_ / 128, H_), 256, 0, stream>>>(
        Qs, Kb, Pchunk, rsum, b);
    pv_gemm<<<dim3(1, S_ / 128, H_), 256, 0, stream>>>(
        Pchunk, Vt, rsum, ctxb16, b);
    attn_avg<<<S_, 256, 0, stream>>>(
        Pchunk, rsum + (size_t)b * H_ * S_, out_attn + (size_t)b * S_ * S_);
  }

  // 3) ypre = ctx @ out_w^T + out_b + x (MFMA, fp32 epilogue)
  gemm_mfma_out<<<dim3(E_ / 128, B_ * S_ / 128), 256, 0, stream>>>(
      ctxb16, owb, out_b, x, ypre);

  // 4) LN row stats
  ln_stats_kernel<<<B_ * S_, 256, 0, stream>>>(ypre, stats);

  // 5) context = mean over s of LN(ypre)*g + b (two-stage)
  context_partial<<<dim3(E_ / 256, B_, 16), 256, 0, stream>>>(ypre, stats, part);
  context_final<<<B_ * E_ / 256, 256, 0, stream>>>(part, ln_g, ln_b, out_ctx);
}